// Round 10
// baseline (318.606 us; speedup 1.0000x reference)
//
#include <hip/hip_runtime.h>

// Fused single-head attention: q,k,v = x@W{q,k,v}+b; softmax(q k^T/32) v
// B=8, S=2048, d_model=dk=dv=1024. Inputs fp32; compute in bf16 MFMA.
// GEMM: 128x256 tile, BK=32, 8 waves, 48KB LDS dbuf, 2 blocks/CU, using
// mfma_f32_32x32x16_bf16 (4096 FLOP/cyc pipe vs 3400 for 16x16x32; half
// the MFMA instruction count at identical LDS traffic).
// Softmax fused in QK epilogue (exp2 once per score, no max needed:
// |q.k|/32*log2e <= ~3); reduce_ml -> Li; PV pure GEMM scaled by Li.

#define DEV __device__ __forceinline__

typedef unsigned short u16;
typedef __attribute__((ext_vector_type(8))) short bf16x8;
typedef __attribute__((ext_vector_type(16))) float f32x16;

DEV float bf2f(u16 u) {
  unsigned v = ((unsigned)u) << 16;
  float f;
  __builtin_memcpy(&f, &v, 4);
  return f;
}
DEV u16 f2bf(float f) {
  unsigned v;
  __builtin_memcpy(&v, &f, 4);
  return (u16)((v + 0x7fffu + ((v >> 16) & 1u)) >> 16);
}

DEV void gload16(const u16* g, u16* l) {
  __builtin_amdgcn_global_load_lds(
      (const __attribute__((address_space(1))) void*)g,
      (__attribute__((address_space(3))) void*)l, 16, 0, 0);
}

#define BAR() __builtin_amdgcn_s_barrier()
#define SCHED0() __builtin_amdgcn_sched_barrier(0)
#define LGKM0() asm volatile("s_waitcnt lgkmcnt(0)" ::: "memory")
#define VMC(n) asm volatile("s_waitcnt vmcnt(" #n ")" ::: "memory")

// --------------------------------------------------------------- prep
// blocks [0,16384): x fp32 -> xb bf16 (float4/thread)
// blocks [16384, 16384+768): W transpose+convert, 64x64 tiles x 3 weights
__global__ __launch_bounds__(256) void prep(const float* __restrict__ x,
                                            const float* __restrict__ Wq,
                                            const float* __restrict__ Wk,
                                            const float* __restrict__ Wv,
                                            u16* __restrict__ xb,
                                            u16* __restrict__ Wt) {
  __shared__ float tl[64][65];
  const int tid = threadIdx.x;
  if (blockIdx.x < 16384) {
    const long long i = ((long long)blockIdx.x * 256 + tid) * 4;
    float4 v = *(const float4*)&x[i];
    ushort4 o;
    o.x = f2bf(v.x); o.y = f2bf(v.y); o.z = f2bf(v.z); o.w = f2bf(v.w);
    *(ushort4*)&xb[i] = o;
    return;
  }
  const int b = blockIdx.x - 16384;
  const int bz = b >> 8, byk = (b >> 4) & 15, bxn = b & 15;
  const float* W = bz == 0 ? Wq : bz == 1 ? Wk : Wv;
  u16* dst = Wt + (long long)bz * 1048576LL;
  const int n0 = bxn * 64, k0 = byk * 64;
  const int c = tid & 31, r = tid >> 5;
#pragma unroll
  for (int i = 0; i < 8; ++i) {
    const int k = i * 8 + r;
    float2 v2 = *(const float2*)&W[(long long)(k0 + k) * 1024 + n0 + c * 2];
    tl[k][c * 2] = v2.x;
    tl[k][c * 2 + 1] = v2.y;
  }
  __syncthreads();
#pragma unroll
  for (int i = 0; i < 8; ++i) {
    const int n = i * 8 + r;
    ushort2 o;
    o.x = f2bf(tl[c * 2][n]);
    o.y = f2bf(tl[c * 2 + 1][n]);
    *(ushort2*)&dst[(long long)(n0 + n) * 1024 + k0 + c * 2] = o;
  }
}

// ---------------------------------------------------------- row-sum reduce
__global__ __launch_bounds__(256) void reduce_ml(const float* __restrict__ PS,
                                                 float* __restrict__ Li) {
  const int i = blockIdx.x * 256 + threadIdx.x;  // 0..16383
  const int z = i >> 11, r = i & 2047;
  const float* ps = PS + ((long long)(z * 8) << 11) + r;
  float L = 0.f;
#pragma unroll
  for (int p = 0; p < 8; ++p) L += ps[p << 11];
  Li[i] = 1.0f / L;
}

// ----------------------------------------------- 128x256 BK=32 GEMM (32x32)
// C[m][n] = sum_k A[m][k] * B[n][k]  (both bf16 row-major, K-contiguous)
// 512 thr = 8 waves (2M x 4N); per-wave C = 64x64 = 2x2 frags of 32x32
// (acc = 4 x f32x16 = 64 regs). LDS 48KB: buf[0,1] (24KB) = A[128][32k]
// (8KB) + B[256][32k] (16KB); row = 64B = 4 slots of 16B, slot swizzle
// s' = s ^ ((row>>1)&3); DMA linear dest + pre-swizzled global k-seg.
// Frag layouts (mfma_f32_32x32x16_bf16):
//   A/B in:  row = lane&31, k = kk*16 + (lane>>5)*8 + j  (j<8)
//   C/D out: col = lane&31, row = (reg&3) + 8*(reg>>2) + 4*(lane>>5) [m101]
// Per tile t (buf BO): RD 8 b128; lgkm(0); BAR; STG(t+2->BO); vmcnt(3);
// 8 MFMA (setprio); BAR.   2 blocks/CU.
// OUT_MODE: 0 = bf16 + (z?pm:bias)[col] (z-selected bias, merged QK proj)
//           1 = P = exp2(acc*scale) bf16 + row-sum partials (ps)
//           3 = bf16 + bias[row]
//           4 = f32 scaled by pm[row] (Li)

template <int OUT_MODE>
__global__ __launch_bounds__(512, 4) void gemm32(
    const u16* __restrict__ A, const u16* __restrict__ B,
    const float* __restrict__ bias, void* __restrict__ Cv, int K, int lda,
    int ldb, int ldc, long long bA, long long bB, long long bC, float scale,
    const float* __restrict__ pm, float* __restrict__ ps) {
  __shared__ __attribute__((aligned(16))) char smem[49152];
  const int tid = threadIdx.x;
  const int w = tid >> 6, l = tid & 63;
  const int wr = w >> 2, wc = w & 3;  // 2 row-halves x 4 col-quarters

  // T1: bijective chunked XCD swizzle (all grids have nwg % 8 == 0)
  const int gx = gridDim.x, gy = gridDim.y;
  long long flat =
      blockIdx.x + (long long)gx * (blockIdx.y + (long long)gy * blockIdx.z);
  const long long nwg = (long long)gx * gy * gridDim.z;
  if ((nwg & 7) == 0) flat = (flat & 7) * (nwg >> 3) + (flat >> 3);
  const int bx = (int)(flat % gx);
  const long long rem = flat / gx;
  const int by = (int)(rem % gy);
  const int z = (int)(rem / gy);

  A += (long long)z * bA;
  B += (long long)z * bB;
  const long long tm = (long long)by * 128;
  const long long tn = (long long)bx * 256;

  // LDS read bases: lane reads row base + (l&31); k-slot kk*2 + (l>>5),
  // swizzled by ((row>>1)&3) (row>>1 mod 4 == (l31>>1)&3 since bases are
  // multiples of 32 rows).
  const int l31 = l & 31, h = l >> 5;
  const int xsw = (l31 >> 1) & 3;
  const int sl0 = ((0 * 2 + h) ^ xsw) * 16;  // kk=0
  const int sl1 = ((1 * 2 + h) ^ xsw) * 16;  // kk=1
  const char* bAr = smem + (wr * 64 + l31) * 64;          // + mi*2048 + sl + BO
  const char* bBr = smem + 8192 + (wc * 64 + l31) * 64;   // + ni*2048 + sl + BO

  // staging: thread t loads row t>>2, k-seg (t&3)^((t>>3)&3), 16B
  const int srow = tid >> 2;
  const int kseg = (tid & 3) ^ ((tid >> 3) & 3);
  const int tid16 = tid * 16;
  const u16* pA = A + (tm + srow) * (long long)lda + kseg * 8;
  const u16* pB0 = B + (tn + srow) * (long long)ldb + kseg * 8;
  const u16* pB1 = B + (tn + 128 + srow) * (long long)ldb + kseg * 8;

#define STG(BO)                                           \
  gload16(pA, (u16*)(smem + (BO) + tid16));               \
  gload16(pB0, (u16*)(smem + (BO) + 8192 + tid16));       \
  gload16(pB1, (u16*)(smem + (BO) + 16384 + tid16));      \
  pA += 32;                                               \
  pB0 += 32;                                              \
  pB1 += 32;

#define RDAB(BO)                                            \
  afr[0][0] = *(const bf16x8*)(bAr + (BO) + sl0);           \
  afr[0][1] = *(const bf16x8*)(bAr + (BO) + sl1);           \
  afr[1][0] = *(const bf16x8*)(bAr + (BO) + 2048 + sl0);    \
  afr[1][1] = *(const bf16x8*)(bAr + (BO) + 2048 + sl1);    \
  bfr[0][0] = *(const bf16x8*)(bBr + (BO) + sl0);           \
  bfr[0][1] = *(const bf16x8*)(bBr + (BO) + sl1);           \
  bfr[1][0] = *(const bf16x8*)(bBr + (BO) + 2048 + sl0);    \
  bfr[1][1] = *(const bf16x8*)(bBr + (BO) + 2048 + sl1);

#define MFMAT()                                                           \
  __builtin_amdgcn_s_setprio(1);                                          \
  _Pragma("unroll") for (int ni = 0; ni < 2; ++ni)                        \
      _Pragma("unroll") for (int mi = 0; mi < 2; ++mi) {                  \
    acc[mi][ni] = __builtin_amdgcn_mfma_f32_32x32x16_bf16(                \
        afr[mi][0], bfr[ni][0], acc[mi][ni], 0, 0, 0);                    \
    acc[mi][ni] = __builtin_amdgcn_mfma_f32_32x32x16_bf16(                \
        afr[mi][1], bfr[ni][1], acc[mi][ni], 0, 0, 0);                    \
  }                                                                       \
  __builtin_amdgcn_s_setprio(0);

#define TILE(BO, T)                  \
  RDAB(BO);                          \
  LGKM0();                           \
  SCHED0();                          \
  BAR();                             \
  if ((T) + 2 < nt) {                \
    STG(BO);                         \
    VMC(3);                          \
  } else {                           \
    VMC(0);                          \
  }                                  \
  SCHED0();                          \
  MFMAT();                           \
  SCHED0();                          \
  BAR();

  f32x16 acc[2][2];
#pragma unroll
  for (int i = 0; i < 2; ++i)
#pragma unroll
    for (int j = 0; j < 2; ++j)
#pragma unroll
      for (int e = 0; e < 16; ++e) acc[i][j][e] = 0.f;

  bf16x8 afr[2][2], bfr[2][2];
  const int nt = K >> 5;  // requires nt even, >= 4

  // prologue: tile0 -> buf0, tile1 -> buf1; wait tile0
  STG(0);
  STG(24576);
  VMC(3);
  BAR();

  for (int t = 0; t < nt; t += 2) {
    TILE(0, t);
    TILE(24576, t + 1);
  }

  // epilogue: 32x32 C/D: col = l&31, row = (reg&3) + 8*(reg>>2) + 4*h
  if (OUT_MODE == 4) {
    float* C = (float*)Cv + (long long)z * bC;
#pragma unroll
    for (int mi = 0; mi < 2; ++mi) {
      const long long rb = tm + wr * 64 + mi * 32;
      float lir[16];
#pragma unroll
      for (int rg = 0; rg < 16; ++rg)
        lir[rg] = pm[(long long)z * 2048 + rb + (rg & 3) + 8 * (rg >> 2) + 4 * h];
#pragma unroll
      for (int ni = 0; ni < 2; ++ni) {
        const long long col = tn + wc * 64 + ni * 32 + l31;
#pragma unroll
        for (int rg = 0; rg < 16; ++rg) {
          const long long row = rb + (rg & 3) + 8 * (rg >> 2) + 4 * h;
          C[row * ldc + col] = acc[mi][ni][rg] * lir[rg];
        }
      }
    }
  } else if (OUT_MODE == 1) {
    // P = exp2(acc * scale) bf16 (scale folds 1/32 * log2e); row-sum
    // partials to ps. No max subtraction: |acc*scale| <= ~3.
    u16* C = (u16*)Cv + (long long)z * bC;
    float* lps = (float*)smem;  // [128][4] per-wc partials (2 KB)
#pragma unroll
    for (int mi = 0; mi < 2; ++mi) {
      const long long rb = tm + wr * 64 + mi * 32;
#pragma unroll
      for (int rg = 0; rg < 16; ++rg) {
        const int rloc = (rg & 3) + 8 * (rg >> 2) + 4 * h;
        const long long row = rb + rloc;
        float s_ = 0.f;
#pragma unroll
        for (int ni = 0; ni < 2; ++ni) {
          const float e = __builtin_amdgcn_exp2f(acc[mi][ni][rg] * scale);
          s_ += e;
          C[row * ldc + tn + wc * 64 + ni * 32 + l31] = f2bf(e);
        }
#pragma unroll
        for (int off = 1; off < 32; off <<= 1) s_ += __shfl_xor(s_, off, 64);
        if (l31 == 0) lps[(wr * 64 + mi * 32 + rloc) * 4 + wc] = s_;
      }
    }
    __syncthreads();
    if (tid < 128) {
      const float S = lps[tid * 4] + lps[tid * 4 + 1] + lps[tid * 4 + 2] +
                      lps[tid * 4 + 3];
      ps[(((long long)z * 8 + bx) << 11) + tm + tid] = S;
    }
  } else if (OUT_MODE == 0) {
    u16* C = (u16*)Cv + (long long)z * bC;
    const float* bb = z ? pm : bias;  // z-selected bias (merged Q/K proj)
#pragma unroll
    for (int mi = 0; mi < 2; ++mi) {
      const long long rb = tm + wr * 64 + mi * 32;
#pragma unroll
      for (int ni = 0; ni < 2; ++ni) {
        const long long col = tn + wc * 64 + ni * 32 + l31;
        const float badd = bb[col];
#pragma unroll
        for (int rg = 0; rg < 16; ++rg) {
          const long long row = rb + (rg & 3) + 8 * (rg >> 2) + 4 * h;
          C[row * ldc + col] = f2bf(acc[mi][ni][rg] + badd);
        }
      }
    }
  } else {  // OUT_MODE == 3: bias[row]
    u16* C = (u16*)Cv + (long long)z * bC;
#pragma unroll
    for (int mi = 0; mi < 2; ++mi) {
      const long long rb = tm + wr * 64 + mi * 32;
#pragma unroll
      for (int rg = 0; rg < 16; ++rg) {
        const long long row = rb + (rg & 3) + 8 * (rg >> 2) + 4 * h;
        const float badd = bias[row];
#pragma unroll
        for (int ni = 0; ni < 2; ++ni) {
          const long long col = tn + wc * 64 + ni * 32 + l31;
          C[row * ldc + col] = f2bf(acc[mi][ni][rg] + badd);
        }
      }
    }
  }
}

// ---------------------------------------------------------------- launch
extern "C" void kernel_launch(void* const* d_in, const int* in_sizes, int n_in,
                              void* d_out, int out_size, void* d_ws,
                              size_t ws_size, hipStream_t stream) {
  const float* x = (const float*)d_in[0];
  const float* Wq = (const float*)d_in[1];
  const float* bq = (const float*)d_in[2];
  const float* Wk = (const float*)d_in[3];
  const float* bk = (const float*)d_in[4];
  const float* Wv = (const float*)d_in[5];
  const float* bv = (const float*)d_in[6];
  float* out = (float*)d_out;

  const long long MT = 16384LL;
  const long long D = 1024LL;

  u16* ws = (u16*)d_ws;
  u16* Wt = ws;                  // 3 x 1048576 (dead after projections)
  u16* Q = Wt + 3 * 1048576LL;   // 16777216
  u16* Kb = Q + MT * D;          // 16777216 (= Q + 16777216)
  u16* Vt = Kb + MT * D;         // 16777216  [d][b*2048+s]
  u16* SC = Vt + MT * D;         // 33554432  [b][q][s] -> holds P
  u16* xb = SC;                  // overlap: x bf16 (proj phase only)
  // row-sum stats overlay the dead Wt region (QK^T runs after projections)
  float* PSa = (float*)d_ws;     // [8][8][2048]
  float* Li = PSa + 131072;      // [16384]

  // scale folds the 1/sqrt(dk)=1/32 and the exp2 conversion: log2(e)/32
  const float cl2e = 1.4426950408889634f * 0.03125f;

  // x convert + weight transpose, one dispatch
  prep<<<dim3(16384 + 768), dim3(256), 0, stream>>>(x, Wq, Wk, Wv, xb, Wt);
  // merged Q,K projections: z in {0,1} selects Wt slice / bias / output
  gemm32<0><<<dim3(4, 128, 2), dim3(512), 0, stream>>>(
      xb, Wt, bq, Q, 1024, 1024, 1024, 1024, 0, 1048576LL, 16777216LL, 0.f,
      bk, nullptr);
  // V^T directly: Vt[d][bs] = sum_k WvT[d][k]*xb[bs][k] + bv[d]
  gemm32<3><<<dim3(64, 8, 1), dim3(512), 0, stream>>>(
      Wt + 2097152LL, xb, bv, Vt, 1024, 1024, 1024, 16384, 0, 0, 0, 0.f,
      nullptr, nullptr);
  // P = exp2(Q K^T * cl2e) (bf16) + row-sum partials into PSa
  gemm32<1><<<dim3(8, 16, 8), dim3(512), 0, stream>>>(
      Q, Kb, nullptr, SC, 1024, 1024, 1024, 2048, 2048 * 1024LL, 2048 * 1024LL,
      2048LL * 2048LL, cl2e, nullptr, PSa);
  // Li = 1 / row-sum
  reduce_ml<<<dim3(64), dim3(256), 0, stream>>>(PSa, Li);
  // out = (P @ V) * Li  (fp32 to d_out)
  gemm32<4><<<dim3(4, 16, 8), dim3(512), 0, stream>>>(
      SC, Vt, nullptr, out, 2048, 2048, 16384, 1024, 2048LL * 2048LL, 2048LL,
      2048 * 1024LL, 0.f, Li, nullptr);
}

// Round 11
// 303.503 us; speedup vs baseline: 1.0498x; 1.0498x over previous
//
#include <hip/hip_runtime.h>

// Fused single-head attention: q,k,v = x@W{q,k,v}+b; softmax(q k^T/32) v
// B=8, S=2048, d_model=dk=dv=1024. Inputs fp32; compute in bf16 MFMA.
// GEMM: R7's 256x256 / BK=64 / 8-wave schedule (LDS layout, staging,
// barriers, vmcnt/lgkm counts IDENTICAL to the proven R7 kernel) with the
// MFMA shape swapped to mfma_f32_32x32x16_bf16 (4060 vs 3377 FLOP/cyc/CU,
// half the MFMA instruction count). 128B LDS rows + slot^(row&7) swizzle
// = the empirically conflict-free config (R3-R8: 0 conflicts).
// Softmax fused in QK epilogue (exp2 once per score, no max needed:
// |q.k|/32*log2e <= ~3); reduce_ml -> Li; PV pure GEMM scaled by Li.

#define DEV __device__ __forceinline__

typedef unsigned short u16;
typedef __attribute__((ext_vector_type(8))) short bf16x8;
typedef __attribute__((ext_vector_type(16))) float f32x16;

DEV float bf2f(u16 u) {
  unsigned v = ((unsigned)u) << 16;
  float f;
  __builtin_memcpy(&f, &v, 4);
  return f;
}
DEV u16 f2bf(float f) {
  unsigned v;
  __builtin_memcpy(&v, &f, 4);
  return (u16)((v + 0x7fffu + ((v >> 16) & 1u)) >> 16);
}

DEV void gload16(const u16* g, u16* l) {
  __builtin_amdgcn_global_load_lds(
      (const __attribute__((address_space(1))) void*)g,
      (__attribute__((address_space(3))) void*)l, 16, 0, 0);
}

#define BAR() __builtin_amdgcn_s_barrier()
#define SCHED0() __builtin_amdgcn_sched_barrier(0)
#define LGKM(n) asm volatile("s_waitcnt lgkmcnt(" #n ")" ::: "memory")
#define VMC6() asm volatile("s_waitcnt vmcnt(6)" ::: "memory")
#define VMC0() asm volatile("s_waitcnt vmcnt(0)" ::: "memory")

// --------------------------------------------------------------- prep
// blocks [0,16384): x fp32 -> xb bf16 (float4/thread)
// blocks [16384, 16384+768): W transpose+convert, 64x64 tiles x 3 weights
__global__ __launch_bounds__(256) void prep(const float* __restrict__ x,
                                            const float* __restrict__ Wq,
                                            const float* __restrict__ Wk,
                                            const float* __restrict__ Wv,
                                            u16* __restrict__ xb,
                                            u16* __restrict__ Wt) {
  __shared__ float tl[64][65];
  const int tid = threadIdx.x;
  if (blockIdx.x < 16384) {
    const long long i = ((long long)blockIdx.x * 256 + tid) * 4;
    float4 v = *(const float4*)&x[i];
    ushort4 o;
    o.x = f2bf(v.x); o.y = f2bf(v.y); o.z = f2bf(v.z); o.w = f2bf(v.w);
    *(ushort4*)&xb[i] = o;
    return;
  }
  const int b = blockIdx.x - 16384;
  const int bz = b >> 8, byk = (b >> 4) & 15, bxn = b & 15;
  const float* W = bz == 0 ? Wq : bz == 1 ? Wk : Wv;
  u16* dst = Wt + (long long)bz * 1048576LL;
  const int n0 = bxn * 64, k0 = byk * 64;
  const int c = tid & 31, r = tid >> 5;
#pragma unroll
  for (int i = 0; i < 8; ++i) {
    const int k = i * 8 + r;
    float2 v2 = *(const float2*)&W[(long long)(k0 + k) * 1024 + n0 + c * 2];
    tl[k][c * 2] = v2.x;
    tl[k][c * 2 + 1] = v2.y;
  }
  __syncthreads();
#pragma unroll
  for (int i = 0; i < 8; ++i) {
    const int n = i * 8 + r;
    ushort2 o;
    o.x = f2bf(tl[c * 2][n]);
    o.y = f2bf(tl[c * 2 + 1][n]);
    *(ushort2*)&dst[(long long)(n0 + n) * 1024 + k0 + c * 2] = o;
  }
}

// ---------------------------------------------------------- row-sum reduce
__global__ __launch_bounds__(256) void reduce_ml(const float* __restrict__ PS,
                                                 float* __restrict__ Li) {
  const int i = blockIdx.x * 256 + threadIdx.x;  // 0..16383
  const int z = i >> 11, r = i & 2047;
  const float* ps = PS + ((long long)(z * 8) << 11) + r;
  float L = 0.f;
#pragma unroll
  for (int p = 0; p < 8; ++p) L += ps[p << 11];
  Li[i] = 1.0f / L;
}

// --------------------------------------------- 256^2 BK=64 GEMM, 32x32 MFMA
// C[m][n] = sum_k A[m][k] * B[n][k]  (both bf16 row-major, K-contiguous)
// 512 thr = 8 waves (2 M-rows x 4 N-cols); per-wave C = 128x64 = 4x2 frags
// of 32x32 (acc = 8 x f32x16 = 128 regs, same budget as R7's f32x4[8][4]).
// LDS 128KB: buf[0,1] (64KB) = parts {0:B-up,1:B-lo,2:A-up,3:A-lo}, each
// [128 rows][64 k] bf16 = 16KB; row = 128B = 8 slots of 16B; swizzle
// slot' = slot ^ (row&7). Staging IDENTICAL to R7 (linear gload_lds dest,
// pre-swizzled global source).
// Frag layouts (mfma_f32_32x32x16_bf16, HW-verified m74/m101 + R10 pass):
//   A/B in:  row = lane&31, k = kk*16 + (lane>>5)*8 + j  -> slot kk*2+(l>>5)
//   C/D out: col = lane&31, row = (reg&3) + 8*(reg>>2) + 4*(lane>>5)
// Schedule per tile t (BO=t&1, OBO=other) -- R7's skeleton verbatim:
//  p0: rd frag-row1; stg A-lo(t+1)->OBO; BAR; lgkm(4); MFMA fr0; BAR
//  p1: rd frag-row2; stg B-up(t+2)->BO;  BAR; lgkm(4); MFMA fr1; BAR
//  p2: rd frag-row3; stg B-lo(t+2)->BO;  BAR; lgkm(4); MFMA fr2; BAR
//  p3: stg A-up(t+2)->BO; vmcnt(6) [vmcnt(0) tail]; BAR;
//      rd frag-row0(t+1); lgkm(4); MFMA fr3; rd B(t+1); BAR
// OUT_MODE: 0 = bf16 + bias[col]; 1 = P = exp2(acc*scale) bf16 + row-sum
// partials (ps); 3 = bf16 + bias[row]; 4 = f32 scaled by pm[row] (Li).

template <int OUT_MODE>
__global__ __launch_bounds__(512, 2) void gemm256(
    const u16* __restrict__ A, const u16* __restrict__ B,
    const float* __restrict__ bias, void* __restrict__ Cv, int K, int lda,
    int ldb, int ldc, long long bA, long long bB, long long bC, float scale,
    const float* __restrict__ pm, float* __restrict__ ps) {
  __shared__ __attribute__((aligned(16))) char smem[131072];
  const int tid = threadIdx.x;
  const int w = tid >> 6, l = tid & 63;
  const int wr = w >> 2, wc = w & 3;

  // T1: bijective chunked XCD swizzle (all grids have nwg % 8 == 0)
  const int gx = gridDim.x, gy = gridDim.y;
  long long flat =
      blockIdx.x + (long long)gx * (blockIdx.y + (long long)gy * blockIdx.z);
  const long long nwg = (long long)gx * gy * gridDim.z;
  if ((nwg & 7) == 0) flat = (flat & 7) * (nwg >> 3) + (flat >> 3);
  const int bx = (int)(flat % gx);
  const long long rem = flat / gx;
  const int by = (int)(rem % gy);
  const int z = (int)(rem / gy);

  A += (long long)z * bA;
  B += (long long)z * bB;
  const long long tm = (long long)by * 256;
  const long long tn = (long long)bx * 256;

  // per-lane LDS read bases. 32x32 frag: row = l&31, slot = kk*2 + (l>>5),
  // swizzled ^ (row&7) = ^(l31&7). Reads become base + imm (fr/ni * 4096).
  const int l31 = l & 31, h = l >> 5, x7 = l31 & 7;
  const int sl0 = ((0 + h) ^ x7) * 16;
  const int sl1 = ((2 + h) ^ x7) * 16;
  const int sl2 = ((4 + h) ^ x7) * 16;
  const int sl3 = ((6 + h) ^ x7) * 16;
  const char* bAr = smem + (2 + wr) * 16384 + l31 * 128;  // + fr*4096 + sl + BO
  const char* bBr = smem + (wc >> 1) * 16384 + ((wc & 1) * 64 + l31) * 128;

  // hoisted global stage pointers (IDENTICAL to R7)
  const int lr = l >> 3;
  const long long scol = (long long)(((l & 7) ^ lr) * 8);
  const u16* pBu0 = B + (tn + w * 16 + 0 + lr) * (long long)ldb + scol;
  const u16* pBu1 = B + (tn + w * 16 + 8 + lr) * (long long)ldb + scol;
  const u16* pBl0 = B + (tn + 128 + w * 16 + 0 + lr) * (long long)ldb + scol;
  const u16* pBl1 = B + (tn + 128 + w * 16 + 8 + lr) * (long long)ldb + scol;
  const u16* pAu0 = A + (tm + w * 16 + 0 + lr) * (long long)lda + scol;
  const u16* pAu1 = A + (tm + w * 16 + 8 + lr) * (long long)lda + scol;
  const u16* pAl0 = A + (tm + 128 + w * 16 + 0 + lr) * (long long)lda + scol;
  const u16* pAl1 = A + (tm + 128 + w * 16 + 8 + lr) * (long long)lda + scol;

#define STG(P0, P1, PART, BO)                                          \
  gload16(P0, (u16*)(smem + (BO) + (PART) * 16384 + (w * 2) * 1024));  \
  gload16(P1, (u16*)(smem + (BO) + (PART) * 16384 + (w * 2 + 1) * 1024)); \
  P0 += 64;                                                            \
  P1 += 64;

#define RDB(BO)                                                      \
  _Pragma("unroll") for (int ni = 0; ni < 2; ++ni) {                 \
    bfrag[ni][0] = *(const bf16x8*)(bBr + (BO) + ni * 4096 + sl0);   \
    bfrag[ni][1] = *(const bf16x8*)(bBr + (BO) + ni * 4096 + sl1);   \
    bfrag[ni][2] = *(const bf16x8*)(bBr + (BO) + ni * 4096 + sl2);   \
    bfrag[ni][3] = *(const bf16x8*)(bBr + (BO) + ni * 4096 + sl3);   \
  }

#define RDF(DST, FR, BO)                                  \
  DST[0] = *(const bf16x8*)(bAr + (BO) + (FR)*4096 + sl0); \
  DST[1] = *(const bf16x8*)(bAr + (BO) + (FR)*4096 + sl1); \
  DST[2] = *(const bf16x8*)(bAr + (BO) + (FR)*4096 + sl2); \
  DST[3] = *(const bf16x8*)(bAr + (BO) + (FR)*4096 + sl3);

#define MFMAF(ACR, AP)                                                   \
  __builtin_amdgcn_s_setprio(1);                                         \
  _Pragma("unroll") for (int kk = 0; kk < 4; ++kk)                       \
      _Pragma("unroll") for (int ni = 0; ni < 2; ++ni)                   \
          ACR[ni] = __builtin_amdgcn_mfma_f32_32x32x16_bf16(             \
              AP[kk], bfrag[ni][kk], ACR[ni], 0, 0, 0);                  \
  __builtin_amdgcn_s_setprio(0);

#define KTILE(BO, OBO, T)                          \
  RDF(aB_, 1, BO);                                 \
  if ((T) + 1 < nt) { STG(pAl0, pAl1, 3, OBO); }   \
  BAR();                                           \
  LGKM(4);                                         \
  SCHED0();                                        \
  MFMAF(acc[0], aA);                               \
  BAR();                                           \
  RDF(aA, 2, BO);                                  \
  if ((T) + 2 < nt) { STG(pBu0, pBu1, 0, BO); }    \
  BAR();                                           \
  LGKM(4);                                         \
  SCHED0();                                        \
  MFMAF(acc[1], aB_);                              \
  BAR();                                           \
  RDF(aB_, 3, BO);                                 \
  if ((T) + 2 < nt) { STG(pBl0, pBl1, 1, BO); }    \
  BAR();                                           \
  LGKM(4);                                         \
  SCHED0();                                        \
  MFMAF(acc[2], aA);                               \
  BAR();                                           \
  if ((T) + 2 < nt) {                              \
    STG(pAu0, pAu1, 2, BO);                        \
    VMC6();                                        \
  } else {                                         \
    VMC0();                                        \
  }                                                \
  BAR();                                           \
  if ((T) + 1 < nt) { RDF(aA, 0, OBO); }           \
  LGKM(4);                                         \
  SCHED0();                                        \
  MFMAF(acc[3], aB_);                              \
  if ((T) + 1 < nt) { RDB(OBO); }                  \
  BAR();

  f32x16 acc[4][2];
#pragma unroll
  for (int i = 0; i < 4; ++i)
#pragma unroll
    for (int j = 0; j < 2; ++j)
#pragma unroll
      for (int e = 0; e < 16; ++e) acc[i][j][e] = 0.f;

  bf16x8 bfrag[2][4], aA[4], aB_[4];
  const int nt = K >> 6;  // requires nt even, >= 4

  // prologue: tile0 {Bu,Bl,Au,Al}@k0 -> buf0; tile1 {Bu,Bl,Au}@k64 -> buf1
  STG(pBu0, pBu1, 0, 0);
  STG(pBl0, pBl1, 1, 0);
  STG(pAu0, pAu1, 2, 0);
  STG(pAl0, pAl1, 3, 0);
  STG(pBu0, pBu1, 0, 65536);
  STG(pBl0, pBl1, 1, 65536);
  STG(pAu0, pAu1, 2, 65536);
  VMC6();  // tile0's 8 loads landed (tile1's 6 may fly)
  BAR();
  // prime tile0 frags: frag-row0 + all B (12 reads; p0's LGKM(4) covers)
  RDF(aA, 0, 0);
  RDB(0);

  for (int t = 0; t < nt; t += 2) {
    KTILE(0, 65536, t);
    KTILE(65536, 0, t + 1);
  }

  // epilogue: 32x32 C/D: col = l&31, row = (rg&3) + 8*(rg>>2) + 4*h
  if (OUT_MODE == 4) {
    float* C = (float*)Cv + (long long)z * bC;
#pragma unroll
    for (int fr = 0; fr < 4; ++fr) {
      const long long rb = tm + wr * 128 + fr * 32;
      float lir[16];
#pragma unroll
      for (int rg = 0; rg < 16; ++rg)
        lir[rg] =
            pm[(long long)z * 2048 + rb + (rg & 3) + 8 * (rg >> 2) + 4 * h];
#pragma unroll
      for (int ni = 0; ni < 2; ++ni) {
        const long long col = tn + wc * 64 + ni * 32 + l31;
#pragma unroll
        for (int rg = 0; rg < 16; ++rg) {
          const long long row = rb + (rg & 3) + 8 * (rg >> 2) + 4 * h;
          C[row * ldc + col] = acc[fr][ni][rg] * lir[rg];
        }
      }
    }
  } else if (OUT_MODE == 1) {
    // P = exp2(acc * scale) bf16 (scale folds 1/32 * log2e); row-sum
    // partials to ps. No max subtraction: |acc*scale| <= ~3.
    u16* C = (u16*)Cv + (long long)z * bC;
    float* lps = (float*)smem;  // [256][4] per-wc partials (4 KB)
#pragma unroll
    for (int fr = 0; fr < 4; ++fr) {
      const long long rb = tm + wr * 128 + fr * 32;
#pragma unroll
      for (int rg = 0; rg < 16; ++rg) {
        const int rloc = (rg & 3) + 8 * (rg >> 2) + 4 * h;
        const long long row = rb + rloc;
        float s_ = 0.f;
#pragma unroll
        for (int ni = 0; ni < 2; ++ni) {
          const float e = __builtin_amdgcn_exp2f(acc[fr][ni][rg] * scale);
          s_ += e;
          C[row * ldc + tn + wc * 64 + ni * 32 + l31] = f2bf(e);
        }
#pragma unroll
        for (int off = 1; off < 32; off <<= 1) s_ += __shfl_xor(s_, off, 64);
        if (l31 == 0) lps[(wr * 128 + fr * 32 + rloc) * 4 + wc] = s_;
      }
    }
    __syncthreads();
    if (tid < 256) {
      const float S = lps[tid * 4] + lps[tid * 4 + 1] + lps[tid * 4 + 2] +
                      lps[tid * 4 + 3];
      ps[(((long long)z * 8 + bx) << 11) + tm + tid] = S;
    }
  } else if (OUT_MODE == 0) {
    u16* C = (u16*)Cv + (long long)z * bC;
#pragma unroll
    for (int fr = 0; fr < 4; ++fr) {
      const long long rb = tm + wr * 128 + fr * 32;
#pragma unroll
      for (int ni = 0; ni < 2; ++ni) {
        const long long col = tn + wc * 64 + ni * 32 + l31;
        const float badd = bias[col];
#pragma unroll
        for (int rg = 0; rg < 16; ++rg) {
          const long long row = rb + (rg & 3) + 8 * (rg >> 2) + 4 * h;
          C[row * ldc + col] = f2bf(acc[fr][ni][rg] + badd);
        }
      }
    }
  } else {  // OUT_MODE == 3: bias[row]
    u16* C = (u16*)Cv + (long long)z * bC;
#pragma unroll
    for (int fr = 0; fr < 4; ++fr) {
      const long long rb = tm + wr * 128 + fr * 32;
#pragma unroll
      for (int rg = 0; rg < 16; ++rg) {
        const long long row = rb + (rg & 3) + 8 * (rg >> 2) + 4 * h;
        const float badd = bias[row];
#pragma unroll
        for (int ni = 0; ni < 2; ++ni) {
          const long long col = tn + wc * 64 + ni * 32 + l31;
          C[row * ldc + col] = f2bf(acc[fr][ni][rg] + badd);
        }
      }
    }
  }
}

// ---------------------------------------------------------------- launch
extern "C" void kernel_launch(void* const* d_in, const int* in_sizes, int n_in,
                              void* d_out, int out_size, void* d_ws,
                              size_t ws_size, hipStream_t stream) {
  const float* x = (const float*)d_in[0];
  const float* Wq = (const float*)d_in[1];
  const float* bq = (const float*)d_in[2];
  const float* Wk = (const float*)d_in[3];
  const float* bk = (const float*)d_in[4];
  const float* Wv = (const float*)d_in[5];
  const float* bv = (const float*)d_in[6];
  float* out = (float*)d_out;

  const long long MT = 16384LL;
  const long long D = 1024LL;

  u16* ws = (u16*)d_ws;
  u16* Wt = ws;                  // 3 x 1048576 (dead after projections)
  u16* Q = Wt + 3 * 1048576LL;   // 16777216
  u16* Kb = Q + MT * D;          // 16777216
  u16* Vt = Kb + MT * D;         // 16777216  [d][b*2048+s]
  u16* SC = Vt + MT * D;         // 33554432  [b][q][s] -> holds P
  u16* xb = SC;                  // overlap: x bf16 (proj phase only)
  // row-sum stats overlay the dead Wt region (QK^T runs after projections)
  float* PSa = (float*)d_ws;     // [8][8][2048]
  float* Li = PSa + 131072;      // [16384]

  // scale folds the 1/sqrt(dk)=1/32 and the exp2 conversion: log2(e)/32
  const float cl2e = 1.4426950408889634f * 0.03125f;

  // x convert + weight transpose, one dispatch
  prep<<<dim3(16384 + 768), dim3(256), 0, stream>>>(x, Wq, Wk, Wv, xb, Wt);
  // Q,K projections: [16384,1024] = xb @ Wt^T + b
  gemm256<0><<<dim3(4, 64, 1), dim3(512), 0, stream>>>(
      xb, Wt, bq, Q, 1024, 1024, 1024, 1024, 0, 0, 0, 0.f, nullptr, nullptr);
  gemm256<0><<<dim3(4, 64, 1), dim3(512), 0, stream>>>(
      xb, Wt + 1048576LL, bk, Kb, 1024, 1024, 1024, 1024, 0, 0, 0, 0.f,
      nullptr, nullptr);
  // V^T directly: Vt[d][bs] = sum_k WvT[d][k]*xb[bs][k] + bv[d]
  gemm256<3><<<dim3(64, 4, 1), dim3(512), 0, stream>>>(
      Wt + 2097152LL, xb, bv, Vt, 1024, 1024, 1024, 16384, 0, 0, 0, 0.f,
      nullptr, nullptr);
  // P = exp2(Q K^T * cl2e) (bf16) + row-sum partials into PSa
  gemm256<1><<<dim3(8, 8, 8), dim3(512), 0, stream>>>(
      Q, Kb, nullptr, SC, 1024, 1024, 1024, 2048, 2048 * 1024LL, 2048 * 1024LL,
      2048LL * 2048LL, cl2e, nullptr, PSa);
  // Li = 1 / row-sum
  reduce_ml<<<dim3(64), dim3(256), 0, stream>>>(PSa, Li);
  // out = (P @ V) * Li  (fp32 to d_out)
  gemm256<4><<<dim3(4, 8, 8), dim3(512), 0, stream>>>(
      SC, Vt, nullptr, out, 2048, 2048, 16384, 1024, 2048LL * 2048LL, 2048LL,
      2048 * 1024LL, 0.f, Li, nullptr);
}

// Round 12
// 273.198 us; speedup vs baseline: 1.1662x; 1.1109x over previous
//
#include <hip/hip_runtime.h>

// Fused single-head attention: q,k,v = x@W{q,k,v}+b; softmax(q k^T/32) v
// B=8, S=2048, d_model=dk=dv=1024. Inputs fp32; compute in bf16 MFMA.
// GEMM: R7's proven 256x256 / BK=64 / 8-wave / 16x16x32 schedule (best
// measured, 0 LDS conflicts). This round: all three projections merged
// into ONE 768-block dispatch (OUT_MODE 6, flat-decoded Q/K/V groups).
// Softmax fused in QK epilogue (exp2 once per score, no max needed:
// |q.k|/32*log2e <= ~3); reduce_ml -> Li; PV pure GEMM scaled by Li.

#define DEV __device__ __forceinline__

typedef unsigned short u16;
typedef __attribute__((ext_vector_type(8))) short bf16x8;
typedef __attribute__((ext_vector_type(4))) float f32x4;

DEV float bf2f(u16 u) {
  unsigned v = ((unsigned)u) << 16;
  float f;
  __builtin_memcpy(&f, &v, 4);
  return f;
}
DEV u16 f2bf(float f) {
  unsigned v;
  __builtin_memcpy(&v, &f, 4);
  return (u16)((v + 0x7fffu + ((v >> 16) & 1u)) >> 16);
}

DEV void gload16(const u16* g, u16* l) {
  __builtin_amdgcn_global_load_lds(
      (const __attribute__((address_space(1))) void*)g,
      (__attribute__((address_space(3))) void*)l, 16, 0, 0);
}

#define BAR() __builtin_amdgcn_s_barrier()
#define SCHED0() __builtin_amdgcn_sched_barrier(0)
#define LGKM(n) asm volatile("s_waitcnt lgkmcnt(" #n ")" ::: "memory")
#define VMC6() asm volatile("s_waitcnt vmcnt(6)" ::: "memory")
#define VMC0() asm volatile("s_waitcnt vmcnt(0)" ::: "memory")

// --------------------------------------------------------------- prep
// blocks [0,16384): x fp32 -> xb bf16 (float4/thread)
// blocks [16384, 16384+768): W transpose+convert, 64x64 tiles x 3 weights
__global__ __launch_bounds__(256) void prep(const float* __restrict__ x,
                                            const float* __restrict__ Wq,
                                            const float* __restrict__ Wk,
                                            const float* __restrict__ Wv,
                                            u16* __restrict__ xb,
                                            u16* __restrict__ Wt) {
  __shared__ float tl[64][65];
  const int tid = threadIdx.x;
  if (blockIdx.x < 16384) {
    const long long i = ((long long)blockIdx.x * 256 + tid) * 4;
    float4 v = *(const float4*)&x[i];
    ushort4 o;
    o.x = f2bf(v.x); o.y = f2bf(v.y); o.z = f2bf(v.z); o.w = f2bf(v.w);
    *(ushort4*)&xb[i] = o;
    return;
  }
  const int b = blockIdx.x - 16384;
  const int bz = b >> 8, byk = (b >> 4) & 15, bxn = b & 15;
  const float* W = bz == 0 ? Wq : bz == 1 ? Wk : Wv;
  u16* dst = Wt + (long long)bz * 1048576LL;
  const int n0 = bxn * 64, k0 = byk * 64;
  const int c = tid & 31, r = tid >> 5;
#pragma unroll
  for (int i = 0; i < 8; ++i) {
    const int k = i * 8 + r;
    float2 v2 = *(const float2*)&W[(long long)(k0 + k) * 1024 + n0 + c * 2];
    tl[k][c * 2] = v2.x;
    tl[k][c * 2 + 1] = v2.y;
  }
  __syncthreads();
#pragma unroll
  for (int i = 0; i < 8; ++i) {
    const int n = i * 8 + r;
    ushort2 o;
    o.x = f2bf(tl[c * 2][n]);
    o.y = f2bf(tl[c * 2 + 1][n]);
    *(ushort2*)&dst[(long long)(n0 + n) * 1024 + k0 + c * 2] = o;
  }
}

// ---------------------------------------------------------- row-sum reduce
__global__ __launch_bounds__(256) void reduce_ml(const float* __restrict__ PS,
                                                 float* __restrict__ Li) {
  const int i = blockIdx.x * 256 + threadIdx.x;  // 0..16383
  const int z = i >> 11, r = i & 2047;
  const float* ps = PS + ((long long)(z * 8) << 11) + r;
  float L = 0.f;
#pragma unroll
  for (int p = 0; p < 8; ++p) L += ps[p << 11];
  Li[i] = 1.0f / L;
}

// ------------------------------------------------------- 256^2 8-phase GEMM
// C[m][n] = sum_k A[m][k] * B[n][k]  (both bf16 row-major, K-contiguous)
// 512 thr = 8 waves (2 M-rows x 4 N-cols); per-wave C = 128x64.
// LDS 128KB: buf[0,1] (64KB) = parts {0:B-up,1:B-lo,2:A-up,3:A-lo}, each
// [128 rows][64 k] bf16 = 16KB, XOR-swizzled: 16B-slot s at byte
// r*128 + (s^(r&7))*16 (linear gload_lds dest + pre-swizzled global source).
// Schedule per tile t (R7 verbatim, proven race-free and conflict-free):
//  p0: rd pair1; stg A-lo(t+1)->OBO; BAR; lgkm(4); MFMA pair0; BAR
//  p1: rd pair2; stg B-up(t+2)->BO;  BAR; lgkm(4); MFMA pair1; BAR
//  p2: rd pair3; stg B-lo(t+2)->BO;  BAR; lgkm(4); MFMA pair2; BAR
//  p3: stg A-up(t+2)->BO; vmcnt(6) [vmcnt(0) tail]; BAR;
//      rd pair0(t+1); lgkm(4); MFMA pair3; rd B(t+1); BAR
// OUT_MODE: 1 = P = exp2(acc*scale) bf16 + row-sum partials (ps out)
//           4 = f32 out scaled by pm[row] (Li)
//           6 = fused Q/K/V projections: 768 blocks, grp = flat>>8;
//               grp0: Q = xb@WqT + bq[col];  grp1: K = xb@WkT + pm(bk)[col]
//               grp2: Vt = WvT@xb + ps(bv)[row], ldc=16384

template <int OUT_MODE>
__global__ __launch_bounds__(512, 2) void gemm256(
    const u16* __restrict__ A, const u16* __restrict__ B,
    const float* __restrict__ bias, void* __restrict__ Cv, int K, int lda,
    int ldb, int ldc, long long bA, long long bB, long long bC, float scale,
    const float* __restrict__ pm, float* __restrict__ ps) {
  __shared__ __attribute__((aligned(16))) char smem[131072];
  const int tid = threadIdx.x;
  const int w = tid >> 6, l = tid & 63;
  const int wr = w >> 2, wc = w & 3;

  // T1: bijective chunked XCD swizzle (all grids have nwg % 8 == 0)
  const int gx = gridDim.x, gy = gridDim.y;
  long long flat =
      blockIdx.x + (long long)gx * (blockIdx.y + (long long)gy * blockIdx.z);
  const long long nwg = (long long)gx * gy * gridDim.z;
  if ((nwg & 7) == 0) flat = (flat & 7) * (nwg >> 3) + (flat >> 3);

  const u16* Aop = A;
  const u16* Bop = B;
  int LDA = lda, LDB = ldb, LDC = ldc;
  int bx, by, z, grp = 0;
  if (OUT_MODE == 6) {
    const int g = (int)flat;  // 0..767
    grp = g >> 8;
    const int f = g & 255;
    if (grp < 2) {
      by = f >> 2;  // 64 row-blocks (M=16384)
      bx = f & 3;   // 4 col-blocks (N=1024)
      if (grp == 1) Bop = B + 1048576LL;
    } else {
      by = f >> 6;  // 4 row-blocks (M=1024)
      bx = f & 63;  // 64 col-blocks (N=16384)
      Aop = B + 2097152LL;  // Wv^T
      Bop = A;              // xb
      LDC = 16384;
    }
    z = 0;
  } else {
    bx = (int)(flat % gx);
    const long long rem = flat / gx;
    by = (int)(rem % gy);
    z = (int)(rem / gy);
    Aop += (long long)z * bA;
    Bop += (long long)z * bB;
  }
  const long long tm = (long long)by * 256;
  const long long tn = (long long)bx * 256;

  // per-lane LDS read bases (byte addresses; reads become base + imm)
  const int l15 = l & 15, hi4 = l >> 4, x7 = l & 7;
  const int slot0 = (hi4 ^ x7) * 16;
  const int slot1 = ((4 + hi4) ^ x7) * 16;
  const char* baseA0 = smem + (2 + wr) * 16384 + l15 * 128 + slot0;
  const char* baseA1 = smem + (2 + wr) * 16384 + l15 * 128 + slot1;
  const char* baseB0 =
      smem + (wc >> 1) * 16384 + ((wc & 1) * 64 + l15) * 128 + slot0;
  const char* baseB1 =
      smem + (wc >> 1) * 16384 + ((wc & 1) * 64 + l15) * 128 + slot1;

  // hoisted global stage pointers (advance +64 elems per staged tile)
  const int lr = l >> 3;
  const long long scol = (long long)((x7 ^ lr) * 8);
  const u16* pBu0 = Bop + (tn + w * 16 + 0 + lr) * (long long)LDB + scol;
  const u16* pBu1 = Bop + (tn + w * 16 + 8 + lr) * (long long)LDB + scol;
  const u16* pBl0 = Bop + (tn + 128 + w * 16 + 0 + lr) * (long long)LDB + scol;
  const u16* pBl1 = Bop + (tn + 128 + w * 16 + 8 + lr) * (long long)LDB + scol;
  const u16* pAu0 = Aop + (tm + w * 16 + 0 + lr) * (long long)LDA + scol;
  const u16* pAu1 = Aop + (tm + w * 16 + 8 + lr) * (long long)LDA + scol;
  const u16* pAl0 = Aop + (tm + 128 + w * 16 + 0 + lr) * (long long)LDA + scol;
  const u16* pAl1 = Aop + (tm + 128 + w * 16 + 8 + lr) * (long long)LDA + scol;

#define STG(P0, P1, PART, BO)                                             \
  gload16(P0, (u16*)(smem + (BO) + (PART) * 16384 + (w * 2) * 1024));     \
  gload16(P1, (u16*)(smem + (BO) + (PART) * 16384 + (w * 2 + 1) * 1024)); \
  P0 += 64;                                                               \
  P1 += 64;

#define RDB(BO)                                                 \
  _Pragma("unroll") for (int ni = 0; ni < 4; ++ni) {            \
    bfrag[ni][0] = *(const bf16x8*)(baseB0 + (BO) + ni * 2048); \
    bfrag[ni][1] = *(const bf16x8*)(baseB1 + (BO) + ni * 2048); \
  }

#define RDP(DST, MLO, BO)                                         \
  DST[0][0] = *(const bf16x8*)(baseA0 + (BO) + (MLO)*2048);       \
  DST[0][1] = *(const bf16x8*)(baseA1 + (BO) + (MLO)*2048);       \
  DST[1][0] = *(const bf16x8*)(baseA0 + (BO) + (MLO + 1) * 2048); \
  DST[1][1] = *(const bf16x8*)(baseA1 + (BO) + (MLO + 1) * 2048);

#define MFMAP(AC0, AC1, AP)                                              \
  __builtin_amdgcn_s_setprio(1);                                         \
  _Pragma("unroll") for (int kk = 0; kk < 2; ++kk)                       \
      _Pragma("unroll") for (int ni = 0; ni < 4; ++ni) {                 \
    AC0[ni] = __builtin_amdgcn_mfma_f32_16x16x32_bf16(AP[0][kk],         \
                                                      bfrag[ni][kk],     \
                                                      AC0[ni], 0, 0, 0); \
    AC1[ni] = __builtin_amdgcn_mfma_f32_16x16x32_bf16(AP[1][kk],         \
                                                      bfrag[ni][kk],     \
                                                      AC1[ni], 0, 0, 0); \
  }                                                                      \
  __builtin_amdgcn_s_setprio(0);

#define KTILE(BO, OBO, T)                        \
  RDP(aB_, 2, BO);                               \
  if ((T) + 1 < nt) { STG(pAl0, pAl1, 3, OBO); } \
  BAR();                                         \
  LGKM(4);                                       \
  SCHED0();                                      \
  MFMAP(acc[0], acc[1], aA);                     \
  BAR();                                         \
  RDP(aA, 4, BO);                                \
  if ((T) + 2 < nt) { STG(pBu0, pBu1, 0, BO); }  \
  BAR();                                         \
  LGKM(4);                                       \
  SCHED0();                                      \
  MFMAP(acc[2], acc[3], aB_);                    \
  BAR();                                         \
  RDP(aB_, 6, BO);                               \
  if ((T) + 2 < nt) { STG(pBl0, pBl1, 1, BO); }  \
  BAR();                                         \
  LGKM(4);                                       \
  SCHED0();                                      \
  MFMAP(acc[4], acc[5], aA);                     \
  BAR();                                         \
  if ((T) + 2 < nt) {                            \
    STG(pAu0, pAu1, 2, BO);                      \
    VMC6();                                      \
  } else {                                       \
    VMC0();                                      \
  }                                              \
  BAR();                                         \
  if ((T) + 1 < nt) { RDP(aA, 0, OBO); }         \
  LGKM(4);                                       \
  SCHED0();                                      \
  MFMAP(acc[6], acc[7], aB_);                    \
  if ((T) + 1 < nt) { RDB(OBO); }                \
  BAR();

  f32x4 acc[8][4];
  const f32x4 zero = {0.f, 0.f, 0.f, 0.f};
#pragma unroll
  for (int i = 0; i < 8; ++i)
#pragma unroll
    for (int j = 0; j < 4; ++j) acc[i][j] = zero;

  bf16x8 bfrag[4][2], aA[2][2], aB_[2][2];
  const int nt = K >> 6;  // requires nt even, >= 4

  // prologue: tile0 {Bu,Bl,Au,Al}@k0 -> buf0; tile1 {Bu,Bl,Au}@k64 -> buf1
  STG(pBu0, pBu1, 0, 0);
  STG(pBl0, pBl1, 1, 0);
  STG(pAu0, pAu1, 2, 0);
  STG(pAl0, pAl1, 3, 0);
  STG(pBu0, pBu1, 0, 65536);
  STG(pBl0, pBl1, 1, 65536);
  STG(pAu0, pAu1, 2, 65536);
  VMC6();  // tile0's 8 loads landed (tile1's 6 may fly)
  BAR();
  // prime tile0 frags: pair0 + all B (12 reads, covered by p0's LGKM(4))
  RDP(aA, 0, 0);
  RDB(0);

  for (int t = 0; t < nt; t += 2) {
    KTILE(0, 65536, t);
    KTILE(65536, 0, t + 1);
  }

  // epilogue: C/D layout col = lane&15, row = (lane>>4)*4 + reg
  const int ro4 = (l >> 4) * 4;
  const int co = l & 15;
  if (OUT_MODE == 4) {
    float* C = (float*)Cv + (long long)z * bC;
#pragma unroll
    for (int mi = 0; mi < 8; ++mi) {
      const long long row0 = tm + wr * 128 + mi * 16 + ro4;
      float li[4];
#pragma unroll
      for (int r = 0; r < 4; ++r) li[r] = pm[(long long)z * 2048 + row0 + r];
#pragma unroll
      for (int ni = 0; ni < 4; ++ni) {
        const long long col = tn + wc * 64 + ni * 16 + co;
#pragma unroll
        for (int r = 0; r < 4; ++r)
          C[(row0 + r) * LDC + col] = acc[mi][ni][r] * li[r];
      }
    }
  } else if (OUT_MODE == 1) {
    // P = exp2(acc * scale) bf16 (scale folds 1/32 * log2e); row-sum
    // partials to ps. No max subtraction: |acc*scale| <= ~3.
    u16* C = (u16*)Cv + (long long)z * bC;
    float* lps = (float*)smem;  // [256][4] per-wc partials
#pragma unroll
    for (int mi = 0; mi < 8; ++mi) {
      const long long row0 = tm + wr * 128 + mi * 16 + ro4;
#pragma unroll
      for (int r = 0; r < 4; ++r) {
        float s_ = 0.f;
#pragma unroll
        for (int ni = 0; ni < 4; ++ni) {
          const float e = __builtin_amdgcn_exp2f(acc[mi][ni][r] * scale);
          s_ += e;
          C[(row0 + r) * LDC + tn + wc * 64 + ni * 16 + co] = f2bf(e);
        }
#pragma unroll
        for (int off = 1; off < 16; off <<= 1) s_ += __shfl_xor(s_, off, 64);
        if (co == 0) lps[(wr * 128 + mi * 16 + ro4 + r) * 4 + wc] = s_;
      }
    }
    __syncthreads();
    if (tid < 256) {
      const float S = lps[tid * 4] + lps[tid * 4 + 1] + lps[tid * 4 + 2] +
                      lps[tid * 4 + 3];
      ps[(((long long)z * 8 + bx) << 11) + tm + tid] = S;
    }
  } else if (OUT_MODE == 6) {
    u16* C = (u16*)Cv +
             (grp == 0 ? 0LL : grp == 1 ? 16777216LL : 33554432LL);
    if (grp < 2) {
      const float* bb = grp ? pm : bias;  // bq or bk
#pragma unroll
      for (int mi = 0; mi < 8; ++mi) {
        const long long row0 = tm + wr * 128 + mi * 16 + ro4;
#pragma unroll
        for (int ni = 0; ni < 4; ++ni) {
          const long long col = tn + wc * 64 + ni * 16 + co;
          const float badd = bb[col];
#pragma unroll
          for (int r = 0; r < 4; ++r)
            C[(row0 + r) * LDC + col] = f2bf(acc[mi][ni][r] + badd);
        }
      }
    } else {
      const float* rb_ = (const float*)ps;  // bv, bias[row]
#pragma unroll
      for (int mi = 0; mi < 8; ++mi) {
        const long long row0 = tm + wr * 128 + mi * 16 + ro4;
#pragma unroll
        for (int ni = 0; ni < 4; ++ni) {
          const long long col = tn + wc * 64 + ni * 16 + co;
#pragma unroll
          for (int r = 0; r < 4; ++r)
            C[(row0 + r) * LDC + col] = f2bf(acc[mi][ni][r] + rb_[row0 + r]);
        }
      }
    }
  }
}

// ---------------------------------------------------------------- launch
extern "C" void kernel_launch(void* const* d_in, const int* in_sizes, int n_in,
                              void* d_out, int out_size, void* d_ws,
                              size_t ws_size, hipStream_t stream) {
  const float* x = (const float*)d_in[0];
  const float* Wq = (const float*)d_in[1];
  const float* bq = (const float*)d_in[2];
  const float* Wk = (const float*)d_in[3];
  const float* bk = (const float*)d_in[4];
  const float* Wv = (const float*)d_in[5];
  const float* bv = (const float*)d_in[6];
  float* out = (float*)d_out;

  const long long MT = 16384LL;
  const long long D = 1024LL;

  u16* ws = (u16*)d_ws;
  u16* Wt = ws;                 // 3 x 1048576 (dead after projections)
  u16* Q = Wt + 3 * 1048576LL;  // 16777216
  u16* Kb = Q + MT * D;         // 16777216 (= Q + 16777216)
  u16* Vt = Kb + MT * D;        // 16777216 (= Q + 33554432)  [d][b*2048+s]
  u16* SC = Vt + MT * D;        // 33554432  [b][q][s] -> holds P
  u16* xb = SC;                 // overlap: x bf16 (proj phase only)
  // row-sum stats overlay the dead Wt region (QK^T runs after projections)
  float* PSa = (float*)d_ws;  // [8][8][2048]
  float* Li = PSa + 131072;   // [16384]

  // scale folds the 1/sqrt(dk)=1/32 and the exp2 conversion: log2(e)/32
  const float cl2e = 1.4426950408889634f * 0.03125f;

  // x convert + weight transpose, one dispatch
  prep<<<dim3(16384 + 768), dim3(256), 0, stream>>>(x, Wq, Wk, Wv, xb, Wt);
  // fused Q/K/V projections, one 768-block dispatch (OUT_MODE 6):
  //   grp0: Q = xb @ WqT + bq;  grp1: K = xb @ WkT + bk (via pm);
  //   grp2: Vt = WvT @ xb + bv[row] (via ps), ldc=16384
  gemm256<6><<<dim3(768, 1, 1), dim3(512), 0, stream>>>(
      xb, Wt, bq, Q, 1024, 1024, 1024, 1024, 0, 0, 0, 0.f, bk, (float*)bv);
  // P = exp2(Q K^T * cl2e) (bf16) + row-sum partials into PSa
  gemm256<1><<<dim3(8, 8, 8), dim3(512), 0, stream>>>(
      Q, Kb, nullptr, SC, 1024, 1024, 1024, 2048, 2048 * 1024LL, 2048 * 1024LL,
      2048LL * 2048LL, cl2e, nullptr, PSa);
  // Li = 1 / row-sum
  reduce_ml<<<dim3(64), dim3(256), 0, stream>>>(PSa, Li);
  // out = (P @ V) * Li  (fp32 to d_out)
  gemm256<4><<<dim3(4, 8, 8), dim3(512), 0, stream>>>(
      SC, Vt, nullptr, out, 2048, 2048, 16384, 1024, 2048LL * 2048LL, 2048LL,
      2048 * 1024LL, 0.f, Li, nullptr);
}

// Round 13
// 268.462 us; speedup vs baseline: 1.1868x; 1.0176x over previous
//
#include <hip/hip_runtime.h>

// Fused single-head attention: q,k,v = x@W{q,k,v}+b; softmax(q k^T/32) v
// B=8, S=2048, d_model=dk=dv=1024. Inputs fp32; compute in bf16 MFMA.
// GEMM: proven 256x256 / BK=64 / 8-wave / 16x16x32 schedule (R7, best
// measured: 0 LDS conflicts, ~880-1100 TF/dispatch). Projections kept as
// SEPARATE dispatches (256-block grids keep XCD panel locality; merging
// measured -20% on proj throughput, R12). prep = one fused dispatch.
// Softmax fused in QK epilogue (exp2 once per score, no max needed:
// |q.k|/32*log2e <= ~3); reduce_ml -> Li; PV pure GEMM scaled by Li.

#define DEV __device__ __forceinline__

typedef unsigned short u16;
typedef __attribute__((ext_vector_type(8))) short bf16x8;
typedef __attribute__((ext_vector_type(4))) float f32x4;

DEV float bf2f(u16 u) {
  unsigned v = ((unsigned)u) << 16;
  float f;
  __builtin_memcpy(&f, &v, 4);
  return f;
}
DEV u16 f2bf(float f) {
  unsigned v;
  __builtin_memcpy(&v, &f, 4);
  return (u16)((v + 0x7fffu + ((v >> 16) & 1u)) >> 16);
}

DEV void gload16(const u16* g, u16* l) {
  __builtin_amdgcn_global_load_lds(
      (const __attribute__((address_space(1))) void*)g,
      (__attribute__((address_space(3))) void*)l, 16, 0, 0);
}

#define BAR() __builtin_amdgcn_s_barrier()
#define SCHED0() __builtin_amdgcn_sched_barrier(0)
#define LGKM(n) asm volatile("s_waitcnt lgkmcnt(" #n ")" ::: "memory")
#define VMC6() asm volatile("s_waitcnt vmcnt(6)" ::: "memory")
#define VMC0() asm volatile("s_waitcnt vmcnt(0)" ::: "memory")

// --------------------------------------------------------------- prep
// blocks [0,16384): x fp32 -> xb bf16 (float4/thread)
// blocks [16384, 16384+768): W transpose+convert, 64x64 tiles x 3 weights
__global__ __launch_bounds__(256) void prep(const float* __restrict__ x,
                                            const float* __restrict__ Wq,
                                            const float* __restrict__ Wk,
                                            const float* __restrict__ Wv,
                                            u16* __restrict__ xb,
                                            u16* __restrict__ Wt) {
  __shared__ float tl[64][65];
  const int tid = threadIdx.x;
  if (blockIdx.x < 16384) {
    const long long i = ((long long)blockIdx.x * 256 + tid) * 4;
    float4 v = *(const float4*)&x[i];
    ushort4 o;
    o.x = f2bf(v.x); o.y = f2bf(v.y); o.z = f2bf(v.z); o.w = f2bf(v.w);
    *(ushort4*)&xb[i] = o;
    return;
  }
  const int b = blockIdx.x - 16384;
  const int bz = b >> 8, byk = (b >> 4) & 15, bxn = b & 15;
  const float* W = bz == 0 ? Wq : bz == 1 ? Wk : Wv;
  u16* dst = Wt + (long long)bz * 1048576LL;
  const int n0 = bxn * 64, k0 = byk * 64;
  const int c = tid & 31, r = tid >> 5;
#pragma unroll
  for (int i = 0; i < 8; ++i) {
    const int k = i * 8 + r;
    float2 v2 = *(const float2*)&W[(long long)(k0 + k) * 1024 + n0 + c * 2];
    tl[k][c * 2] = v2.x;
    tl[k][c * 2 + 1] = v2.y;
  }
  __syncthreads();
#pragma unroll
  for (int i = 0; i < 8; ++i) {
    const int n = i * 8 + r;
    ushort2 o;
    o.x = f2bf(tl[c * 2][n]);
    o.y = f2bf(tl[c * 2 + 1][n]);
    *(ushort2*)&dst[(long long)(n0 + n) * 1024 + k0 + c * 2] = o;
  }
}

// ---------------------------------------------------------- row-sum reduce
__global__ __launch_bounds__(256) void reduce_ml(const float* __restrict__ PS,
                                                 float* __restrict__ Li) {
  const int i = blockIdx.x * 256 + threadIdx.x;  // 0..16383
  const int z = i >> 11, r = i & 2047;
  const float* ps = PS + ((long long)(z * 8) << 11) + r;
  float L = 0.f;
#pragma unroll
  for (int p = 0; p < 8; ++p) L += ps[p << 11];
  Li[i] = 1.0f / L;
}

// ------------------------------------------------------- 256^2 8-phase GEMM
// C[m][n] = sum_k A[m][k] * B[n][k]  (both bf16 row-major, K-contiguous)
// 512 thr = 8 waves (2 M-rows x 4 N-cols); per-wave C = 128x64.
// LDS 128KB: buf[0,1] (64KB) = parts {0:B-up,1:B-lo,2:A-up,3:A-lo}, each
// [128 rows][64 k] bf16 = 16KB, XOR-swizzled: 16B-slot s at byte
// r*128 + (s^(r&7))*16 (linear gload_lds dest + pre-swizzled global source).
// Schedule per tile t (proven race-free and conflict-free):
//  p0: rd pair1; stg A-lo(t+1)->OBO; BAR; lgkm(4); MFMA pair0; BAR
//  p1: rd pair2; stg B-up(t+2)->BO;  BAR; lgkm(4); MFMA pair1; BAR
//  p2: rd pair3; stg B-lo(t+2)->BO;  BAR; lgkm(4); MFMA pair2; BAR
//  p3: stg A-up(t+2)->BO; vmcnt(6) [vmcnt(0) tail]; BAR;
//      rd pair0(t+1); lgkm(4); MFMA pair3; rd B(t+1); BAR
// OUT_MODE: 0 = bf16 + bias[col]
//           1 = P = exp2(acc*scale) bf16 + row-sum partials (ps out)
//           3 = bf16 + bias[row]
//           4 = f32 out scaled by pm[row] (Li)

template <int OUT_MODE>
__global__ __launch_bounds__(512, 2) void gemm256(
    const u16* __restrict__ A, const u16* __restrict__ B,
    const float* __restrict__ bias, void* __restrict__ Cv, int K, int lda,
    int ldb, int ldc, long long bA, long long bB, long long bC, float scale,
    const float* __restrict__ pm, float* __restrict__ ps) {
  __shared__ __attribute__((aligned(16))) char smem[131072];
  const int tid = threadIdx.x;
  const int w = tid >> 6, l = tid & 63;
  const int wr = w >> 2, wc = w & 3;

  // T1: bijective chunked XCD swizzle (all grids have nwg % 8 == 0)
  const int gx = gridDim.x, gy = gridDim.y;
  long long flat =
      blockIdx.x + (long long)gx * (blockIdx.y + (long long)gy * blockIdx.z);
  const long long nwg = (long long)gx * gy * gridDim.z;
  if ((nwg & 7) == 0) flat = (flat & 7) * (nwg >> 3) + (flat >> 3);
  const int bx = (int)(flat % gx);
  const long long rem = flat / gx;
  const int by = (int)(rem % gy);
  const int z = (int)(rem / gy);

  A += (long long)z * bA;
  B += (long long)z * bB;
  const long long tm = (long long)by * 256;
  const long long tn = (long long)bx * 256;

  // per-lane LDS read bases (byte addresses; reads become base + imm)
  const int l15 = l & 15, hi4 = l >> 4, x7 = l & 7;
  const int slot0 = (hi4 ^ x7) * 16;
  const int slot1 = ((4 + hi4) ^ x7) * 16;
  const char* baseA0 = smem + (2 + wr) * 16384 + l15 * 128 + slot0;
  const char* baseA1 = smem + (2 + wr) * 16384 + l15 * 128 + slot1;
  const char* baseB0 =
      smem + (wc >> 1) * 16384 + ((wc & 1) * 64 + l15) * 128 + slot0;
  const char* baseB1 =
      smem + (wc >> 1) * 16384 + ((wc & 1) * 64 + l15) * 128 + slot1;

  // hoisted global stage pointers (advance +64 elems per staged tile)
  const int lr = l >> 3;
  const long long scol = (long long)((x7 ^ lr) * 8);
  const u16* pBu0 = B + (tn + w * 16 + 0 + lr) * (long long)ldb + scol;
  const u16* pBu1 = B + (tn + w * 16 + 8 + lr) * (long long)ldb + scol;
  const u16* pBl0 = B + (tn + 128 + w * 16 + 0 + lr) * (long long)ldb + scol;
  const u16* pBl1 = B + (tn + 128 + w * 16 + 8 + lr) * (long long)ldb + scol;
  const u16* pAu0 = A + (tm + w * 16 + 0 + lr) * (long long)lda + scol;
  const u16* pAu1 = A + (tm + w * 16 + 8 + lr) * (long long)lda + scol;
  const u16* pAl0 = A + (tm + 128 + w * 16 + 0 + lr) * (long long)lda + scol;
  const u16* pAl1 = A + (tm + 128 + w * 16 + 8 + lr) * (long long)lda + scol;

#define STG(P0, P1, PART, BO)                                             \
  gload16(P0, (u16*)(smem + (BO) + (PART) * 16384 + (w * 2) * 1024));     \
  gload16(P1, (u16*)(smem + (BO) + (PART) * 16384 + (w * 2 + 1) * 1024)); \
  P0 += 64;                                                               \
  P1 += 64;

#define RDB(BO)                                                 \
  _Pragma("unroll") for (int ni = 0; ni < 4; ++ni) {            \
    bfrag[ni][0] = *(const bf16x8*)(baseB0 + (BO) + ni * 2048); \
    bfrag[ni][1] = *(const bf16x8*)(baseB1 + (BO) + ni * 2048); \
  }

#define RDP(DST, MLO, BO)                                         \
  DST[0][0] = *(const bf16x8*)(baseA0 + (BO) + (MLO)*2048);       \
  DST[0][1] = *(const bf16x8*)(baseA1 + (BO) + (MLO)*2048);       \
  DST[1][0] = *(const bf16x8*)(baseA0 + (BO) + (MLO + 1) * 2048); \
  DST[1][1] = *(const bf16x8*)(baseA1 + (BO) + (MLO + 1) * 2048);

#define MFMAP(AC0, AC1, AP)                                              \
  __builtin_amdgcn_s_setprio(1);                                         \
  _Pragma("unroll") for (int kk = 0; kk < 2; ++kk)                       \
      _Pragma("unroll") for (int ni = 0; ni < 4; ++ni) {                 \
    AC0[ni] = __builtin_amdgcn_mfma_f32_16x16x32_bf16(AP[0][kk],         \
                                                      bfrag[ni][kk],     \
                                                      AC0[ni], 0, 0, 0); \
    AC1[ni] = __builtin_amdgcn_mfma_f32_16x16x32_bf16(AP[1][kk],         \
                                                      bfrag[ni][kk],     \
                                                      AC1[ni], 0, 0, 0); \
  }                                                                      \
  __builtin_amdgcn_s_setprio(0);

#define KTILE(BO, OBO, T)                        \
  RDP(aB_, 2, BO);                               \
  if ((T) + 1 < nt) { STG(pAl0, pAl1, 3, OBO); } \
  BAR();                                         \
  LGKM(4);                                       \
  SCHED0();                                      \
  MFMAP(acc[0], acc[1], aA);                     \
  BAR();                                         \
  RDP(aA, 4, BO);                                \
  if ((T) + 2 < nt) { STG(pBu0, pBu1, 0, BO); }  \
  BAR();                                         \
  LGKM(4);                                       \
  SCHED0();                                      \
  MFMAP(acc[2], acc[3], aB_);                    \
  BAR();                                         \
  RDP(aB_, 6, BO);                               \
  if ((T) + 2 < nt) { STG(pBl0, pBl1, 1, BO); }  \
  BAR();                                         \
  LGKM(4);                                       \
  SCHED0();                                      \
  MFMAP(acc[4], acc[5], aA);                     \
  BAR();                                         \
  if ((T) + 2 < nt) {                            \
    STG(pAu0, pAu1, 2, BO);                      \
    VMC6();                                      \
  } else {                                       \
    VMC0();                                      \
  }                                              \
  BAR();                                         \
  if ((T) + 1 < nt) { RDP(aA, 0, OBO); }         \
  LGKM(4);                                       \
  SCHED0();                                      \
  MFMAP(acc[6], acc[7], aB_);                    \
  if ((T) + 1 < nt) { RDB(OBO); }                \
  BAR();

  f32x4 acc[8][4];
  const f32x4 zero = {0.f, 0.f, 0.f, 0.f};
#pragma unroll
  for (int i = 0; i < 8; ++i)
#pragma unroll
    for (int j = 0; j < 4; ++j) acc[i][j] = zero;

  bf16x8 bfrag[4][2], aA[2][2], aB_[2][2];
  const int nt = K >> 6;  // requires nt even, >= 4

  // prologue: tile0 {Bu,Bl,Au,Al}@k0 -> buf0; tile1 {Bu,Bl,Au}@k64 -> buf1
  STG(pBu0, pBu1, 0, 0);
  STG(pBl0, pBl1, 1, 0);
  STG(pAu0, pAu1, 2, 0);
  STG(pAl0, pAl1, 3, 0);
  STG(pBu0, pBu1, 0, 65536);
  STG(pBl0, pBl1, 1, 65536);
  STG(pAu0, pAu1, 2, 65536);
  VMC6();  // tile0's 8 loads landed (tile1's 6 may fly)
  BAR();
  // prime tile0 frags: pair0 + all B (12 reads, covered by p0's LGKM(4))
  RDP(aA, 0, 0);
  RDB(0);

  for (int t = 0; t < nt; t += 2) {
    KTILE(0, 65536, t);
    KTILE(65536, 0, t + 1);
  }

  // epilogue: C/D layout col = lane&15, row = (lane>>4)*4 + reg
  const int ro4 = (l >> 4) * 4;
  const int co = l & 15;
  if (OUT_MODE == 4) {
    float* C = (float*)Cv + (long long)z * bC;
#pragma unroll
    for (int mi = 0; mi < 8; ++mi) {
      const long long row0 = tm + wr * 128 + mi * 16 + ro4;
      float li[4];
#pragma unroll
      for (int r = 0; r < 4; ++r) li[r] = pm[(long long)z * 2048 + row0 + r];
#pragma unroll
      for (int ni = 0; ni < 4; ++ni) {
        const long long col = tn + wc * 64 + ni * 16 + co;
#pragma unroll
        for (int r = 0; r < 4; ++r)
          C[(row0 + r) * ldc + col] = acc[mi][ni][r] * li[r];
      }
    }
  } else if (OUT_MODE == 1) {
    // P = exp2(acc * scale) bf16 (scale folds 1/32 * log2e); row-sum
    // partials to ps. No max subtraction: |acc*scale| <= ~3.
    u16* C = (u16*)Cv + (long long)z * bC;
    float* lps = (float*)smem;  // [256][4] per-wc partials
#pragma unroll
    for (int mi = 0; mi < 8; ++mi) {
      const long long row0 = tm + wr * 128 + mi * 16 + ro4;
#pragma unroll
      for (int r = 0; r < 4; ++r) {
        float s_ = 0.f;
#pragma unroll
        for (int ni = 0; ni < 4; ++ni) {
          const float e = __builtin_amdgcn_exp2f(acc[mi][ni][r] * scale);
          s_ += e;
          C[(row0 + r) * ldc + tn + wc * 64 + ni * 16 + co] = f2bf(e);
        }
#pragma unroll
        for (int off = 1; off < 16; off <<= 1) s_ += __shfl_xor(s_, off, 64);
        if (co == 0) lps[(wr * 128 + mi * 16 + ro4 + r) * 4 + wc] = s_;
      }
    }
    __syncthreads();
    if (tid < 256) {
      const float S = lps[tid * 4] + lps[tid * 4 + 1] + lps[tid * 4 + 2] +
                      lps[tid * 4 + 3];
      ps[(((long long)z * 8 + bx) << 11) + tm + tid] = S;
    }
  } else {
    u16* C = (u16*)Cv + (long long)z * bC;
#pragma unroll
    for (int mi = 0; mi < 8; ++mi) {
      const long long row0 = tm + wr * 128 + mi * 16 + ro4;
#pragma unroll
      for (int ni = 0; ni < 4; ++ni) {
        const long long col = tn + wc * 64 + ni * 16 + co;
        const float badd = (OUT_MODE == 0) ? bias[col] : 0.f;
#pragma unroll
        for (int r = 0; r < 4; ++r) {
          float v = acc[mi][ni][r];
          if (OUT_MODE == 0) v += badd;
          if (OUT_MODE == 3) v += bias[row0 + r];
          C[(row0 + r) * ldc + col] = f2bf(v);
        }
      }
    }
  }
}

// ---------------------------------------------------------------- launch
extern "C" void kernel_launch(void* const* d_in, const int* in_sizes, int n_in,
                              void* d_out, int out_size, void* d_ws,
                              size_t ws_size, hipStream_t stream) {
  const float* x = (const float*)d_in[0];
  const float* Wq = (const float*)d_in[1];
  const float* bq = (const float*)d_in[2];
  const float* Wk = (const float*)d_in[3];
  const float* bk = (const float*)d_in[4];
  const float* Wv = (const float*)d_in[5];
  const float* bv = (const float*)d_in[6];
  float* out = (float*)d_out;

  const long long MT = 16384LL;
  const long long D = 1024LL;

  u16* ws = (u16*)d_ws;
  u16* Wt = ws;                 // 3 x 1048576 (dead after projections)
  u16* Q = Wt + 3 * 1048576LL;  // 16777216
  u16* Kb = Q + MT * D;         // 16777216
  u16* Vt = Kb + MT * D;        // 16777216  [d][b*2048+s]
  u16* SC = Vt + MT * D;        // 33554432  [b][q][s] -> holds P
  u16* xb = SC;                 // overlap: x bf16 (proj phase only)
  // row-sum stats overlay the dead Wt region (QK^T runs after projections)
  float* PSa = (float*)d_ws;  // [8][8][2048]
  float* Li = PSa + 131072;   // [16384]

  // scale folds the 1/sqrt(dk)=1/32 and the exp2 conversion: log2(e)/32
  const float cl2e = 1.4426950408889634f * 0.03125f;

  // x convert + weight transpose, one dispatch
  prep<<<dim3(16384 + 768), dim3(256), 0, stream>>>(x, Wq, Wk, Wv, xb, Wt);
  // Q,K projections: [16384,1024] = xb @ Wt^T + b  (separate dispatches:
  // 256-block grids keep per-XCD operand-panel locality; merging cost 20%)
  gemm256<0><<<dim3(4, 64, 1), dim3(512), 0, stream>>>(
      xb, Wt, bq, Q, 1024, 1024, 1024, 1024, 0, 0, 0, 0.f, nullptr, nullptr);
  gemm256<0><<<dim3(4, 64, 1), dim3(512), 0, stream>>>(
      xb, Wt + 1048576LL, bk, Kb, 1024, 1024, 1024, 1024, 0, 0, 0, 0.f,
      nullptr, nullptr);
  // V^T directly: Vt[d][bs] = sum_k WvT[d][k]*xb[bs][k] + bv[d]
  gemm256<3><<<dim3(64, 4, 1), dim3(512), 0, stream>>>(
      Wt + 2097152LL, xb, bv, Vt, 1024, 1024, 1024, 16384, 0, 0, 0, 0.f,
      nullptr, nullptr);
  // P = exp2(Q K^T * cl2e) (bf16) + row-sum partials into PSa
  gemm256<1><<<dim3(8, 8, 8), dim3(512), 0, stream>>>(
      Q, Kb, nullptr, SC, 1024, 1024, 1024, 2048, 2048 * 1024LL, 2048 * 1024LL,
      2048LL * 2048LL, cl2e, nullptr, PSa);
  // Li = 1 / row-sum
  reduce_ml<<<dim3(64), dim3(256), 0, stream>>>(PSa, Li);
  // out = (P @ V) * Li  (fp32 to d_out)
  gemm256<4><<<dim3(4, 8, 8), dim3(512), 0, stream>>>(
      SC, Vt, nullptr, out, 2048, 2048, 16384, 1024, 2048LL * 2048LL, 2048LL,
      2048 * 1024LL, 0.f, Li, nullptr);
}